// Round 2
// baseline (610.184 us; speedup 1.0000x reference)
//
#include <hip/hip_runtime.h>

#define NTOK 98
#define CDIM 128
#define SCALE 0.17677669529663687f

typedef short bf16x8 __attribute__((ext_vector_type(8)));
typedef float f32x4 __attribute__((ext_vector_type(4)));

__device__ __forceinline__ unsigned short f2bf(float f) {
  union { float f; unsigned u; } v; v.f = f;
  unsigned r = v.u + 0x7FFFu + ((v.u >> 16) & 1u);
  return (unsigned short)(r >> 16);
}

// XOR swizzle for [rows][128] bf16 LDS tiles (kills 16-way conflicts on
// stride-256B ds_read_b128 fragment reads). Element-index form.
__device__ __forceinline__ int swz(int row, int col) {
  return row * 128 + (col ^ ((row & 7) << 3));
}

// Load an 8-wide bf16 fragment (8 consecutive f32) straight from global.
__device__ __forceinline__ bf16x8 ldfrag(const float* __restrict__ p) {
  float4 a = *(const float4*)p;
  float4 b = *(const float4*)(p + 4);
  bf16x8 fr;
  fr[0]=(short)f2bf(a.x); fr[1]=(short)f2bf(a.y); fr[2]=(short)f2bf(a.z); fr[3]=(short)f2bf(a.w);
  fr[4]=(short)f2bf(b.x); fr[5]=(short)f2bf(b.y); fr[6]=(short)f2bf(b.z); fr[7]=(short)f2bf(b.w);
  return fr;
}

__global__ __launch_bounds__(512, 4)
void win_attn_kernel(const float* __restrict__ x,
                     const float* __restrict__ mask,
                     const float* __restrict__ qkv_w,
                     const float* __restrict__ qkv_b,
                     const float* __restrict__ rpb,
                     const float* __restrict__ proj_w,
                     const float* __restrict__ proj_b,
                     float* __restrict__ out, int nW)
{
  // 78 KB total -> 2 blocks/CU (was 148 KB -> 1 block/CU)
  __shared__ __align__(16) unsigned short kb[112 * 128];      // k (all heads); later o
  __shared__ __align__(16) unsigned short vTg[64 * 128];      // v^T for current head-group
  __shared__ __align__(16) unsigned short pbuf[8 * 16 * 128]; // q transit; later per-wave P
  __shared__ short mcode[NTOK];

  const int tid = threadIdx.x;
  const int lane = tid & 63;
  const int wv = tid >> 6;   // wave 0..7
  const int lm = lane & 15;
  const int lg = lane >> 4;
  const int blk = blockIdx.x;
  const float* __restrict__ xblk = x + (size_t)blk * (NTOK * CDIM);
  const float* __restrict__ maskw = mask + (size_t)(blk % nW) * (NTOK * NTOK);

  if (tid < NTOK) {
    int d = tid / 49, rem = tid % 49;
    mcode[tid] = (short)(d * 169 + (rem / 7) * 13 + (rem % 7));
  }

  // ---------------- Phase 1: q -> pbuf, k -> kb (x frags from global) ----------------
  {
    bf16x8 Bq[4], Bk[4];
    const float bq = qkv_b[wv * 16 + lm];
    const float bk_ = qkv_b[128 + wv * 16 + lm];
#pragma unroll
    for (int kk = 0; kk < 4; ++kk) {
      Bq[kk] = ldfrag(qkv_w + (wv * 16 + lm) * CDIM + kk * 32 + lg * 8);
      Bk[kk] = ldfrag(qkv_w + (128 + wv * 16 + lm) * CDIM + kk * 32 + lg * 8);
    }
    for (int mi = 0; mi < 7; ++mi) {
      int arow = mi * 16 + lm; if (arow >= NTOK) arow = NTOK - 1;  // clamp: finite garbage
      bf16x8 A[4];
#pragma unroll
      for (int kk = 0; kk < 4; ++kk)
        A[kk] = ldfrag(xblk + arow * CDIM + kk * 32 + lg * 8);
      f32x4 accq = {0.f,0.f,0.f,0.f}, acck = {0.f,0.f,0.f,0.f};
#pragma unroll
      for (int kk = 0; kk < 4; ++kk) {
        accq = __builtin_amdgcn_mfma_f32_16x16x32_bf16(A[kk], Bq[kk], accq, 0, 0, 0);
        acck = __builtin_amdgcn_mfma_f32_16x16x32_bf16(A[kk], Bk[kk], acck, 0, 0, 0);
      }
#pragma unroll
      for (int r = 0; r < 4; ++r) {
        int mrow = mi * 16 + lg * 4 + r;        // C/D: row=(lane>>4)*4+reg, col=lane&15
        pbuf[swz(mrow, wv * 16 + lm)] = f2bf(accq[r] + bq);
        kb[swz(mrow, wv * 16 + lm)]   = f2bf(acck[r] + bk_);
      }
    }
  }
  __syncthreads();

  // ---- extract per-wave q A-fragments (units: u0 = wv, u1 = wv+8 of 14) ----
  const bool have1 = (wv < 6);
  const int mi0 = wv % 7, hh0 = wv / 7;
  const int mi1 = (wv + 8) % 7;               // hh1 = 1
  bf16x8 aq[2][2];
#pragma unroll
  for (int g = 0; g < 2; ++g) {
    aq[g][0] = *(const bf16x8*)&pbuf[swz(mi0 * 16 + lm, (2 * g + hh0) * 32 + lg * 8)];
    if (have1)
      aq[g][1] = *(const bf16x8*)&pbuf[swz(mi1 * 16 + lm, (2 * g + 1) * 32 + lg * 8)];
  }
  unsigned short* __restrict__ pw = &pbuf[wv * (16 * 128)];

  for (int g = 0; g < 2; ++g) {
    // ---------------- Phase 3g: v(g) -> vTg ----------------
    {
      const int njl = wv >> 1;
      const int mlo = (wv & 1) ? 4 : 0, mhi = (wv & 1) ? 7 : 4;
      bf16x8 Bv[4];
#pragma unroll
      for (int kk = 0; kk < 4; ++kk)
        Bv[kk] = ldfrag(qkv_w + (256 + g * 64 + njl * 16 + lm) * CDIM + kk * 32 + lg * 8);
      const float bv_ = qkv_b[256 + g * 64 + njl * 16 + lm];
      for (int mi = mlo; mi < mhi; ++mi) {
        int arow = mi * 16 + lm; if (arow >= NTOK) arow = NTOK - 1;
        bf16x8 A[4];
#pragma unroll
        for (int kk = 0; kk < 4; ++kk)
          A[kk] = ldfrag(xblk + arow * CDIM + kk * 32 + lg * 8);
        f32x4 acc = {0.f,0.f,0.f,0.f};
#pragma unroll
        for (int kk = 0; kk < 4; ++kk)
          acc = __builtin_amdgcn_mfma_f32_16x16x32_bf16(A[kk], Bv[kk], acc, 0, 0, 0);
#pragma unroll
        for (int r = 0; r < 4; ++r)
          vTg[swz(njl * 16 + lm, mi * 16 + lg * 4 + r)] = f2bf(acc[r] + bv_);  // transposed store
      }
      for (int v2 = tid; v2 < 64 * 16; v2 += 512)   // zero tok pads 112..127 (NaN x 0 guard)
        vTg[swz(v2 >> 4, 112 + (v2 & 15))] = 0;
    }
    __syncthreads();

    // ---------------- Phase 4g: QK^T + softmax + PV, per-wave units ----------------
    f32x4 s0[7], s1[7];
    // ---- unit u0: QK^T + softmax (result: normalized P in s0) ----
    {
      const int h = 2 * g + hh0;
#pragma unroll
      for (int nj = 0; nj < 7; ++nj) {
        bf16x8 bk = *(const bf16x8*)&kb[swz(nj * 16 + lm, h * 32 + lg * 8)];
        f32x4 z = {0.f,0.f,0.f,0.f};
        s0[nj] = __builtin_amdgcn_mfma_f32_16x16x32_bf16(aq[g][0], bk, z, 0, 0, 0);
      }
      int mc_n[7]; bool nval[7];
#pragma unroll
      for (int nj = 0; nj < 7; ++nj) {
        int n = nj * 16 + lm;
        nval[nj] = (n < NTOK);
        mc_n[nj] = mcode[nval[nj] ? n : 0];
      }
#pragma unroll
      for (int r = 0; r < 4; ++r) {
        int m = mi0 * 16 + lg * 4 + r;
        int mc = m < NTOK ? m : NTOK - 1;
        int mcm = mcode[mc];
        const float* mrowp = maskw + mc * NTOK;
        float mx = -1e30f;
#pragma unroll
        for (int nj = 0; nj < 7; ++nj) {
          float val;
          if (nval[nj]) {
            int n = nj * 16 + lm;
            val = s0[nj][r] * SCALE + mrowp[n] + rpb[(mcm - mc_n[nj] + 253) * 4 + h];
          } else val = -1e30f;
          s0[nj][r] = val;
          mx = fmaxf(mx, val);
        }
        mx = fmaxf(mx, __shfl_xor(mx, 1));
        mx = fmaxf(mx, __shfl_xor(mx, 2));
        mx = fmaxf(mx, __shfl_xor(mx, 4));
        mx = fmaxf(mx, __shfl_xor(mx, 8));
        float sum = 0.f;
#pragma unroll
        for (int nj = 0; nj < 7; ++nj) {
          float e = __expf(s0[nj][r] - mx);
          s0[nj][r] = e; sum += e;
        }
        sum += __shfl_xor(sum, 1);
        sum += __shfl_xor(sum, 2);
        sum += __shfl_xor(sum, 4);
        sum += __shfl_xor(sum, 8);
        float inv = 1.f / sum;
#pragma unroll
        for (int nj = 0; nj < 7; ++nj) s0[nj][r] *= inv;
      }
      // write P0 -> per-wave scratch (incl. zero pad cols 112..127)
#pragma unroll
      for (int r = 0; r < 4; ++r) {
        int ml = lg * 4 + r;
#pragma unroll
        for (int nj = 0; nj < 7; ++nj)
          pw[swz(ml, nj * 16 + lm)] = f2bf(s0[nj][r]);
        pw[swz(ml, 112 + lm)] = 0;
      }
    }
    // ---- unit u1: QK^T + softmax, keep normalized P in regs ----
    if (have1) {
      const int h = 2 * g + 1;
#pragma unroll
      for (int nj = 0; nj < 7; ++nj) {
        bf16x8 bk = *(const bf16x8*)&kb[swz(nj * 16 + lm, h * 32 + lg * 8)];
        f32x4 z = {0.f,0.f,0.f,0.f};
        s1[nj] = __builtin_amdgcn_mfma_f32_16x16x32_bf16(aq[g][1], bk, z, 0, 0, 0);
      }
      int mc_n[7]; bool nval[7];
#pragma unroll
      for (int nj = 0; nj < 7; ++nj) {
        int n = nj * 16 + lm;
        nval[nj] = (n < NTOK);
        mc_n[nj] = mcode[nval[nj] ? n : 0];
      }
#pragma unroll
      for (int r = 0; r < 4; ++r) {
        int m = mi1 * 16 + lg * 4 + r;
        int mc = m < NTOK ? m : NTOK - 1;
        int mcm = mcode[mc];
        const float* mrowp = maskw + mc * NTOK;
        float mx = -1e30f;
#pragma unroll
        for (int nj = 0; nj < 7; ++nj) {
          float val;
          if (nval[nj]) {
            int n = nj * 16 + lm;
            val = s1[nj][r] * SCALE + mrowp[n] + rpb[(mcm - mc_n[nj] + 253) * 4 + h];
          } else val = -1e30f;
          s1[nj][r] = val;
          mx = fmaxf(mx, val);
        }
        mx = fmaxf(mx, __shfl_xor(mx, 1));
        mx = fmaxf(mx, __shfl_xor(mx, 2));
        mx = fmaxf(mx, __shfl_xor(mx, 4));
        mx = fmaxf(mx, __shfl_xor(mx, 8));
        float sum = 0.f;
#pragma unroll
        for (int nj = 0; nj < 7; ++nj) {
          float e = __expf(s1[nj][r] - mx);
          s1[nj][r] = e; sum += e;
        }
        sum += __shfl_xor(sum, 1);
        sum += __shfl_xor(sum, 2);
        sum += __shfl_xor(sum, 4);
        sum += __shfl_xor(sum, 8);
        float inv = 1.f / sum;
#pragma unroll
        for (int nj = 0; nj < 7; ++nj) s1[nj][r] *= inv;
      }
    }
    __syncthreads();   // all QK^T(g) reads of kb done -> o cols [g*64, g*64+64) writable

    // ---- PV u0 (reads own pw + vTg, writes o into kb) ----
    {
      const int h = 2 * g + hh0;
      bf16x8 ap[4];
#pragma unroll
      for (int kk = 0; kk < 4; ++kk)
        ap[kk] = *(const bf16x8*)&pw[swz(lm, kk * 32 + lg * 8)];
#pragma unroll
      for (int nt = 0; nt < 2; ++nt) {
        f32x4 acc = {0.f,0.f,0.f,0.f};
#pragma unroll
        for (int kk = 0; kk < 4; ++kk) {
          bf16x8 bv = *(const bf16x8*)&vTg[swz(hh0 * 32 + nt * 16 + lm, kk * 32 + lg * 8)];
          acc = __builtin_amdgcn_mfma_f32_16x16x32_bf16(ap[kk], bv, acc, 0, 0, 0);
        }
#pragma unroll
        for (int r = 0; r < 4; ++r)
          kb[swz(mi0 * 16 + lg * 4 + r, h * 32 + nt * 16 + lm)] = f2bf(acc[r]);
      }
    }
    // ---- write P1, PV u1 ----
    if (have1) {
      asm volatile("s_waitcnt lgkmcnt(0)" ::: "memory");  // PV(u0) pw reads drained
#pragma unroll
      for (int r = 0; r < 4; ++r) {
        int ml = lg * 4 + r;
#pragma unroll
        for (int nj = 0; nj < 7; ++nj)
          pw[swz(ml, nj * 16 + lm)] = f2bf(s1[nj][r]);
        pw[swz(ml, 112 + lm)] = 0;
      }
      const int h = 2 * g + 1;
      bf16x8 ap[4];
#pragma unroll
      for (int kk = 0; kk < 4; ++kk)
        ap[kk] = *(const bf16x8*)&pw[swz(lm, kk * 32 + lg * 8)];
#pragma unroll
      for (int nt = 0; nt < 2; ++nt) {
        f32x4 acc = {0.f,0.f,0.f,0.f};
#pragma unroll
        for (int kk = 0; kk < 4; ++kk) {
          bf16x8 bv = *(const bf16x8*)&vTg[swz(32 + nt * 16 + lm, kk * 32 + lg * 8)];
          acc = __builtin_amdgcn_mfma_f32_16x16x32_bf16(ap[kk], bv, acc, 0, 0, 0);
        }
#pragma unroll
        for (int r = 0; r < 4; ++r)
          kb[swz(mi1 * 16 + lg * 4 + r, h * 32 + nt * 16 + lm)] = f2bf(acc[r]);
      }
    }
    __syncthreads();
  }

  // ---------------- GEMM3: out = o @ Wproj^T + b (o lives in kb) ----------------
  {
    bf16x8 Bp[4];
#pragma unroll
    for (int kk = 0; kk < 4; ++kk)
      Bp[kk] = ldfrag(proj_w + (wv * 16 + lm) * CDIM + kk * 32 + lg * 8);
    const float pb = proj_b[wv * 16 + lm];
    float* __restrict__ outb = out + (size_t)blk * (NTOK * CDIM);
    for (int mi = 0; mi < 7; ++mi) {
      f32x4 acc = {0.f,0.f,0.f,0.f};
#pragma unroll
      for (int kk = 0; kk < 4; ++kk) {
        bf16x8 A = *(const bf16x8*)&kb[swz(mi * 16 + lm, kk * 32 + lg * 8)];
        acc = __builtin_amdgcn_mfma_f32_16x16x32_bf16(A, Bp[kk], acc, 0, 0, 0);
      }
#pragma unroll
      for (int r = 0; r < 4; ++r) {
        int m = mi * 16 + lg * 4 + r;
        if (m < NTOK) outb[m * CDIM + wv * 16 + lm] = acc[r] + pb;
      }
    }
  }
}

extern "C" void kernel_launch(void* const* d_in, const int* in_sizes, int n_in,
                              void* d_out, int out_size, void* d_ws, size_t ws_size,
                              hipStream_t stream) {
  const float* x      = (const float*)d_in[0];
  const float* mask   = (const float*)d_in[1];
  const float* qkv_w  = (const float*)d_in[2];
  const float* qkv_b  = (const float*)d_in[3];
  const float* rpb    = (const float*)d_in[4];
  const float* proj_w = (const float*)d_in[5];
  const float* proj_b = (const float*)d_in[6];
  int B  = in_sizes[0] / (NTOK * CDIM);
  int nW = in_sizes[1] / (NTOK * NTOK);
  hipLaunchKernelGGL(win_attn_kernel, dim3(B), dim3(512), 0, stream,
                     x, mask, qkv_w, qkv_b, rpb, proj_w, proj_b, (float*)d_out, nW);
}

// Round 3
// 350.323 us; speedup vs baseline: 1.7418x; 1.7418x over previous
//
#include <hip/hip_runtime.h>

#define NTOK 98
#define CDIM 128
#define SCALE 0.17677669529663687f

typedef short bf16x8 __attribute__((ext_vector_type(8)));
typedef short bf16x4 __attribute__((ext_vector_type(4)));
typedef float f32x4 __attribute__((ext_vector_type(4)));

#define MFMA32(a,b,c) __builtin_amdgcn_mfma_f32_16x16x32_bf16(a,b,c,0,0,0)

#if __has_builtin(__builtin_amdgcn_mfma_f32_16x16x16_bf16)
#define MFMA16(a,b,c) __builtin_amdgcn_mfma_f32_16x16x16_bf16(a,b,c,0,0,0)
#elif __has_builtin(__builtin_amdgcn_mfma_f32_16x16x16bf16_1k)
#define MFMA16(a,b,c) __builtin_amdgcn_mfma_f32_16x16x16bf16_1k(a,b,c,0,0,0)
#else
__device__ __forceinline__ f32x4 mfma16_asm(bf16x4 a, bf16x4 b, f32x4 c) {
  asm("v_mfma_f32_16x16x16_bf16 %0, %1, %2, %0" : "+v"(c) : "v"(a), "v"(b));
  return c;
}
#define MFMA16(a,b,c) mfma16_asm(a,b,c)
#endif

__device__ __forceinline__ unsigned short f2bf(float f) {
  union { float f; unsigned u; } v; v.f = f;
  unsigned r = v.u + 0x7FFFu + ((v.u >> 16) & 1u);
  return (unsigned short)(r >> 16);
}

// XOR swizzle for [rows][128] bf16 LDS tiles. Flips element bits 3..5 -> safe
// for b64/b128 groups; breaks the stride-256B same-bank pattern (G4/T2).
__device__ __forceinline__ int swz(int row, int col) {
  return row * 128 + (col ^ ((row & 7) << 3));
}

__device__ __forceinline__ bf16x8 ldfrag(const float* __restrict__ p) {
  float4 a = *(const float4*)p;
  float4 b = *(const float4*)(p + 4);
  bf16x8 fr;
  fr[0]=(short)f2bf(a.x); fr[1]=(short)f2bf(a.y); fr[2]=(short)f2bf(a.z); fr[3]=(short)f2bf(a.w);
  fr[4]=(short)f2bf(b.x); fr[5]=(short)f2bf(b.y); fr[6]=(short)f2bf(b.z); fr[7]=(short)f2bf(b.w);
  return fr;
}

__global__ __launch_bounds__(512, 4)
void win_attn_kernel(const float* __restrict__ x,
                     const float* __restrict__ mask,
                     const float* __restrict__ qkv_w,
                     const float* __restrict__ qkv_b,
                     const float* __restrict__ rpb,
                     const float* __restrict__ proj_w,
                     const float* __restrict__ proj_b,
                     float* __restrict__ out, int nW)
{
  // 72.5 KB total -> 2 blocks/CU
  __shared__ __align__(16) unsigned short xs[112 * 128];   // x (staged once, bf16)
  __shared__ __align__(16) unsigned short kb[112 * 128];   // k (all heads); later o
  __shared__ __align__(16) unsigned short vTg[64 * 128];   // v^T for current head-group
  __shared__ short mcode[NTOK];

  const int tid = threadIdx.x;
  const int lane = tid & 63;
  const int wv = tid >> 6;      // wave 0..7
  const int lm = lane & 15;
  const int lg = lane >> 4;
  const int blk = blockIdx.x;
  const float* __restrict__ xblk = x + (size_t)blk * (NTOK * CDIM);
  const float* __restrict__ maskw = mask + (size_t)(blk % nW) * (NTOK * NTOK);

  if (tid < NTOK) {
    int d = tid / 49, rem = tid % 49;
    mcode[tid] = (short)(d * 169 + (rem / 7) * 13 + (rem % 7));
  }

  // ---- stage x -> xs (bf16, swizzled); pad rows 98..111 = 0 ----
  for (int v = tid; v < 112 * 32; v += 512) {
    int row = v >> 5, c4 = (v & 31) << 2;
    float4 f = make_float4(0.f, 0.f, 0.f, 0.f);
    if (row < NTOK) f = *(const float4*)(xblk + row * CDIM + c4);
    uint2 u;
    u.x = (unsigned)f2bf(f.x) | ((unsigned)f2bf(f.y) << 16);
    u.y = (unsigned)f2bf(f.z) | ((unsigned)f2bf(f.w) << 16);
    *(uint2*)&xs[swz(row, c4)] = u;
  }
  __syncthreads();

  // v(g) phase: v cols [g*64, g*64+64) -> vTg[chan_local][token] (transposed)
  auto vphase = [&](int g) {
    const int njl = wv >> 1;
    const int mlo = (wv & 1) ? 4 : 0, mhi = (wv & 1) ? 7 : 4;
    bf16x8 Bv[4];
#pragma unroll
    for (int kk = 0; kk < 4; ++kk)
      Bv[kk] = ldfrag(qkv_w + (size_t)(2 * CDIM + g * 64 + njl * 16 + lm) * CDIM + kk * 32 + lg * 8);
    const float bv_ = qkv_b[2 * CDIM + g * 64 + njl * 16 + lm];
    for (int mi = mlo; mi < mhi; ++mi) {
      bf16x8 A[4];
#pragma unroll
      for (int kk = 0; kk < 4; ++kk)
        A[kk] = *(const bf16x8*)&xs[swz(mi * 16 + lm, kk * 32 + lg * 8)];
      f32x4 acc = {0.f, 0.f, 0.f, 0.f};
#pragma unroll
      for (int kk = 0; kk < 4; ++kk) acc = MFMA32(A[kk], Bv[kk], acc);
#pragma unroll
      for (int r = 0; r < 4; ++r)
        vTg[swz(njl * 16 + lm, mi * 16 + lg * 4 + r)] = f2bf(acc[r] + bv_);
    }
  };

  // ---- k (all heads) -> kb, plus v(0) -> vTg ----
  {
    bf16x8 Bk[4];
    const float bk_ = qkv_b[CDIM + wv * 16 + lm];
#pragma unroll
    for (int kk = 0; kk < 4; ++kk)
      Bk[kk] = ldfrag(qkv_w + (size_t)(CDIM + wv * 16 + lm) * CDIM + kk * 32 + lg * 8);
    for (int mi = 0; mi < 7; ++mi) {
      bf16x8 A[4];
#pragma unroll
      for (int kk = 0; kk < 4; ++kk)
        A[kk] = *(const bf16x8*)&xs[swz(mi * 16 + lm, kk * 32 + lg * 8)];
      f32x4 acc = {0.f, 0.f, 0.f, 0.f};
#pragma unroll
      for (int kk = 0; kk < 4; ++kk) acc = MFMA32(A[kk], Bk[kk], acc);
#pragma unroll
      for (int r = 0; r < 4; ++r)
        kb[swz(mi * 16 + lg * 4 + r, wv * 16 + lm)] = f2bf(acc[r] + bk_);
    }
  }
  vphase(0);
  __syncthreads();

  const bool have1 = (wv < 6);
  const int hh0 = wv / 7, mi0 = wv % 7;
  const int mi1 = wv + 1;   // unit u1 = wv+8 -> hh=1, mi=wv+1 (when wv<6)

#pragma unroll
  for (int g = 0; g < 2; ++g) {
    bf16x4 pp[2][7];        // normalized P A-frags, live across the barrier

#pragma unroll
    for (int j = 0; j < 2; ++j) {
      if (j == 0 || have1) {
        const int hh = j ? 1 : hh0, mi = j ? mi1 : mi0;
        const int h = 2 * g + hh, cb = h * 32;

        // ---- q (swapped MFMA): lane holds q[m=lm][c=cb+ct*16+lg*4+r] ----
        bf16x8 Xf[4];
#pragma unroll
        for (int kk = 0; kk < 4; ++kk)
          Xf[kk] = *(const bf16x8*)&xs[swz(mi * 16 + lm, kk * 32 + lg * 8)];
        bf16x4 bq[2];
#pragma unroll
        for (int ct = 0; ct < 2; ++ct) {
          f32x4 acc = {0.f, 0.f, 0.f, 0.f};
#pragma unroll
          for (int kk = 0; kk < 4; ++kk)
            acc = MFMA32(ldfrag(qkv_w + (size_t)(cb + ct * 16 + lm) * CDIM + kk * 32 + lg * 8),
                         Xf[kk], acc);
#pragma unroll
          for (int r = 0; r < 4; ++r)
            bq[ct][r] = (short)f2bf(acc[r] + qkv_b[cb + ct * 16 + lg * 4 + r]);
        }

        // ---- QK^T swapped: lane holds S[m=lm][n=nj*16+lg*4+r] ----
        f32x4 s[7];
#pragma unroll
        for (int nj = 0; nj < 7; ++nj) {
          bf16x4 k0 = *(const bf16x4*)&kb[swz(nj * 16 + lm, cb + lg * 4)];
          bf16x4 k1 = *(const bf16x4*)&kb[swz(nj * 16 + lm, cb + 16 + lg * 4)];
          f32x4 acc = {0.f, 0.f, 0.f, 0.f};
          acc = MFMA16(k0, bq[0], acc);
          acc = MFMA16(k1, bq[1], acc);
          s[nj] = acc;
        }

        // ---- softmax: row m=lm local 28 vals + 2 shuffles ----
        const int m = mi * 16 + lm;
        const int mc = m < NTOK ? m : NTOK - 1;   // clamp pad rows -> finite
        const int mcm = mcode[mc];
        const float* __restrict__ mrow = maskw + mc * NTOK;
        const int nb0 = lg * 4;
        float mx = -1e30f;
#pragma unroll
        for (int nj = 0; nj < 7; ++nj) {
          const int nb = nj * 16 + nb0;
          float va0, va1, va2, va3;
          if (nb < NTOK) {        // nb even -> pair fully valid & 8B-aligned
            float2 p = *(const float2*)(mrow + nb);
            va0 = s[nj][0] * SCALE + p.x + rpb[(mcm - mcode[nb] + 253) * 4 + h];
            va1 = s[nj][1] * SCALE + p.y + rpb[(mcm - mcode[nb + 1] + 253) * 4 + h];
          } else { va0 = va1 = -1e30f; }
          if (nb + 2 < NTOK) {
            float2 p = *(const float2*)(mrow + nb + 2);
            va2 = s[nj][2] * SCALE + p.x + rpb[(mcm - mcode[nb + 2] + 253) * 4 + h];
            va3 = s[nj][3] * SCALE + p.y + rpb[(mcm - mcode[nb + 3] + 253) * 4 + h];
          } else { va2 = va3 = -1e30f; }
          s[nj][0] = va0; s[nj][1] = va1; s[nj][2] = va2; s[nj][3] = va3;
          mx = fmaxf(mx, fmaxf(fmaxf(va0, va1), fmaxf(va2, va3)));
        }
        mx = fmaxf(mx, __shfl_xor(mx, 16));
        mx = fmaxf(mx, __shfl_xor(mx, 32));
        float sum = 0.f;
#pragma unroll
        for (int nj = 0; nj < 7; ++nj) {
#pragma unroll
          for (int r = 0; r < 4; ++r) {
            float e = __expf(s[nj][r] - mx);
            s[nj][r] = e; sum += e;
          }
        }
        sum += __shfl_xor(sum, 16);
        sum += __shfl_xor(sum, 32);
        const float inv = 1.f / sum;
#pragma unroll
        for (int nj = 0; nj < 7; ++nj) {
          bf16x4 t;
#pragma unroll
          for (int r = 0; r < 4; ++r) t[r] = (short)f2bf(s[nj][r] * inv);
          pp[j][nj] = t;
        }
      }
    }
    __syncthreads();   // all kb reads for group g done -> o cols writable

    // ---- PV: o tile -> kb cols [g*64, g*64+64) ----
#pragma unroll
    for (int j = 0; j < 2; ++j) {
      if (j == 0 || have1) {
        const int hh = j ? 1 : hh0, mi = j ? mi1 : mi0;
        const int h = 2 * g + hh;
#pragma unroll
        for (int dt = 0; dt < 2; ++dt) {
          f32x4 acc = {0.f, 0.f, 0.f, 0.f};
#pragma unroll
          for (int nj = 0; nj < 7; ++nj) {
            bf16x4 bv = *(const bf16x4*)&vTg[swz(hh * 32 + dt * 16 + lm, nj * 16 + lg * 4)];
            acc = MFMA16(pp[j][nj], bv, acc);
          }
#pragma unroll
          for (int r = 0; r < 4; ++r)
            kb[swz(mi * 16 + lg * 4 + r, h * 32 + dt * 16 + lm)] = f2bf(acc[r]);
        }
      }
    }
    __syncthreads();
    if (g == 0) {
      vphase(1);
      __syncthreads();
    }
  }

  // ---------------- GEMM3: out = o @ Wproj^T + b (o lives in kb) ----------------
  {
    bf16x8 Bp[4];
#pragma unroll
    for (int kk = 0; kk < 4; ++kk)
      Bp[kk] = ldfrag(proj_w + (size_t)(wv * 16 + lm) * CDIM + kk * 32 + lg * 8);
    const float pb = proj_b[wv * 16 + lm];
    float* __restrict__ outb = out + (size_t)blk * (NTOK * CDIM);
    for (int mi = 0; mi < 7; ++mi) {
      f32x4 acc = {0.f, 0.f, 0.f, 0.f};
#pragma unroll
      for (int kk = 0; kk < 4; ++kk) {
        bf16x8 A = *(const bf16x8*)&kb[swz(mi * 16 + lm, kk * 32 + lg * 8)];
        acc = MFMA32(A, Bp[kk], acc);
      }
#pragma unroll
      for (int r = 0; r < 4; ++r) {
        int m = mi * 16 + lg * 4 + r;
        if (m < NTOK) outb[m * CDIM + wv * 16 + lm] = acc[r] + pb;
      }
    }
  }
}

extern "C" void kernel_launch(void* const* d_in, const int* in_sizes, int n_in,
                              void* d_out, int out_size, void* d_ws, size_t ws_size,
                              hipStream_t stream) {
  const float* x      = (const float*)d_in[0];
  const float* mask   = (const float*)d_in[1];
  const float* qkv_w  = (const float*)d_in[2];
  const float* qkv_b  = (const float*)d_in[3];
  const float* rpb    = (const float*)d_in[4];
  const float* proj_w = (const float*)d_in[5];
  const float* proj_b = (const float*)d_in[6];
  int B  = in_sizes[0] / (NTOK * CDIM);
  int nW = in_sizes[1] / (NTOK * NTOK);
  hipLaunchKernelGGL(win_attn_kernel, dim3(B), dim3(512), 0, stream,
                     x, mask, qkv_w, qkv_b, rpb, proj_w, proj_b, (float*)d_out, nW);
}

// Round 5
// 282.149 us; speedup vs baseline: 2.1626x; 1.2416x over previous
//
#include <hip/hip_runtime.h>

#define NTOK 98
#define CDIM 128
#define SCALE 0.17677669529663687f

typedef short bf16x8 __attribute__((ext_vector_type(8)));
typedef short bf16x4 __attribute__((ext_vector_type(4)));
typedef float f32x4 __attribute__((ext_vector_type(4)));

#define MFMA32(a,b,c) __builtin_amdgcn_mfma_f32_16x16x32_bf16(a,b,c,0,0,0)

#if __has_builtin(__builtin_amdgcn_mfma_f32_16x16x16_bf16)
#define MFMA16(a,b,c) __builtin_amdgcn_mfma_f32_16x16x16_bf16(a,b,c,0,0,0)
#elif __has_builtin(__builtin_amdgcn_mfma_f32_16x16x16bf16_1k)
#define MFMA16(a,b,c) __builtin_amdgcn_mfma_f32_16x16x16bf16_1k(a,b,c,0,0,0)
#else
__device__ __forceinline__ f32x4 mfma16_asm(bf16x4 a, bf16x4 b, f32x4 c) {
  asm("v_mfma_f32_16x16x16_bf16 %0, %1, %2, %0" : "+v"(c) : "v"(a), "v"(b));
  return c;
}
#define MFMA16(a,b,c) mfma16_asm(a,b,c)
#endif

#define LGKM0() do { asm volatile("s_waitcnt lgkmcnt(0)" ::: "memory"); \
                     __builtin_amdgcn_sched_barrier(0); } while (0)

__device__ __forceinline__ unsigned short f2bf(float f) {
  union { float f; unsigned u; } v; v.f = f;
  unsigned r = v.u + 0x7FFFu + ((v.u >> 16) & 1u);
  return (unsigned short)(r >> 16);
}
__device__ __forceinline__ float bf2f(unsigned short b) {
  union { unsigned u; float f; } v; v.u = ((unsigned)b) << 16; return v.f;
}

// stride-128 tiles (xs, kb): XOR elem-bits 3..5 by row -> b128-safe, kills
// the 256B-stride 16-way bank conflict (G4/T2).
__device__ __forceinline__ int swzK(int row, int col) {
  return row * 128 + (col ^ ((row & 7) << 3));
}
// vbuf [128 d][100 tok]: NO swizzle. Stride 100 elem = 50 dwords; 16
// consecutive d at bank-step 18 (gcd(18,32)=2) hit 16 distinct banks ->
// <=2 lanes/bank per wave access = free (m136). A tail-safe XOR swizzle
// does not exist for stride 100 (R4 bug: partial 16-group at cols 96..99).
__device__ __forceinline__ int idxV(int d, int col) { return d * 100 + col; }

__device__ __forceinline__ bf16x8 ldfrag(const float* __restrict__ p) {
  float4 a = *(const float4*)p;
  float4 b = *(const float4*)(p + 4);
  bf16x8 fr;
  fr[0]=(short)f2bf(a.x); fr[1]=(short)f2bf(a.y); fr[2]=(short)f2bf(a.z); fr[3]=(short)f2bf(a.w);
  fr[4]=(short)f2bf(b.x); fr[5]=(short)f2bf(b.y); fr[6]=(short)f2bf(b.z); fr[7]=(short)f2bf(b.w);
  return fr;
}

__global__ __launch_bounds__(512, 4)
void win_attn_kernel(const float* __restrict__ x,
                     const float* __restrict__ mask,
                     const float* __restrict__ qkv_w,
                     const float* __restrict__ qkv_b,
                     const float* __restrict__ rpb,
                     const float* __restrict__ proj_w,
                     const float* __restrict__ proj_b,
                     float* __restrict__ out, int nW)
{
  // 81.6 KB total -> 2 blocks/CU
  __shared__ __align__(16) unsigned short U[13312];     // xs [98][128]  UNION  8x P[16][104]
  __shared__ __align__(16) unsigned short kbuf[12544];  // k [98][128]; later o
  __shared__ __align__(16) unsigned short vbuf[12800];  // v^T [128 d][100 tok]
  __shared__ __align__(16) unsigned short rpbL[2028];   // rel-pos bias table, bf16 [507][4]
  __shared__ short mcode[112];

  const int tid = threadIdx.x;
  const int lane = tid & 63;
  const int wv = tid >> 6;      // wave 0..7
  const int lm = lane & 15;
  const int lg = lane >> 4;
  const int blk = blockIdx.x;
  const float* __restrict__ xblk = x + (size_t)blk * (NTOK * CDIM);
  const float* __restrict__ maskw = mask + (size_t)(blk % nW) * (NTOK * NTOK);

  if (tid < 112) {
    int c = 0;
    if (tid < NTOK) { int d = tid / 49, rem = tid % 49; c = d * 169 + (rem / 7) * 13 + (rem % 7); }
    mcode[tid] = (short)c;
  }
  for (int i = tid; i < 2028; i += 512) rpbL[i] = f2bf(rpb[i]);
  for (int i = tid; i < 256; i += 512)          // vbuf token-pad cols 98..99 = 0 (NaN x 0 guard)
    vbuf[(i >> 1) * 100 + 98 + (i & 1)] = 0;
  for (int v = tid; v < NTOK * 32; v += 512) {
    int row = v >> 5, c4 = (v & 31) << 2;
    float4 f = *(const float4*)(xblk + row * CDIM + c4);
    uint2 u;
    u.x = (unsigned)f2bf(f.x) | ((unsigned)f2bf(f.y) << 16);
    u.y = (unsigned)f2bf(f.z) | ((unsigned)f2bf(f.w) << 16);
    *(uint2*)&U[swzK(row, c4)] = u;
  }
  __syncthreads();

  // ---------------- prologue: k -> kbuf, v -> vbuf (transposed), q -> regs ----------------
  {
    bf16x8 Bk[4], Bv[4];
    const float bk_ = qkv_b[CDIM + wv * 16 + lm];
    const float bv_ = qkv_b[2 * CDIM + wv * 16 + lm];
#pragma unroll
    for (int kk = 0; kk < 4; ++kk) {
      Bk[kk] = ldfrag(qkv_w + (size_t)(CDIM + wv * 16 + lm) * CDIM + kk * 32 + lg * 8);
      Bv[kk] = ldfrag(qkv_w + (size_t)(2 * CDIM + wv * 16 + lm) * CDIM + kk * 32 + lg * 8);
    }
    for (int mi = 0; mi < 7; ++mi) {
      int arow = mi * 16 + lm; if (arow > 97) arow = 97;   // finite-garbage clamp
      bf16x8 A[4];
#pragma unroll
      for (int kk = 0; kk < 4; ++kk)
        A[kk] = *(const bf16x8*)&U[swzK(arow, kk * 32 + lg * 8)];
      f32x4 ak = {0.f,0.f,0.f,0.f}, av = {0.f,0.f,0.f,0.f};
#pragma unroll
      for (int kk = 0; kk < 4; ++kk) {
        ak = MFMA32(A[kk], Bk[kk], ak);
        av = MFMA32(A[kk], Bv[kk], av);
      }
#pragma unroll
      for (int r = 0; r < 4; ++r) {
        int m = mi * 16 + lg * 4 + r;                      // C/D: row=(lane>>4)*4+r, col=lm
        if (m < NTOK) {
          kbuf[swzK(m, wv * 16 + lm)] = f2bf(ak[r] + bk_);
          vbuf[idxV(wv * 16 + lm, m)] = f2bf(av[r] + bv_); // transposed store
        }
      }
    }
  }

  const bool have1 = (wv < 6);
  const int hh0 = wv / 7, mi0 = wv % 7;
  const int mi1 = wv + 1;                                  // unit u1 = wv+8 -> hh=1 (when wv<6)

  // q C/D held in regs (bf16, bias folded), bounced to LDS after the barrier
  unsigned short qb[2][2][2][4];                           // [j][g][ct][r]
#pragma unroll
  for (int j = 0; j < 2; ++j) {
    if (j == 0 || have1) {
      const int mi = j ? mi1 : mi0;
      int arow = mi * 16 + lm; if (arow > 97) arow = 97;
      bf16x8 A[4];
#pragma unroll
      for (int kk = 0; kk < 4; ++kk)
        A[kk] = *(const bf16x8*)&U[swzK(arow, kk * 32 + lg * 8)];
#pragma unroll
      for (int g = 0; g < 2; ++g) {
        const int cb = (2 * g + (j ? 1 : hh0)) * 32;
#pragma unroll
        for (int ct = 0; ct < 2; ++ct) {
          f32x4 acc = {0.f,0.f,0.f,0.f};
#pragma unroll
          for (int kk = 0; kk < 4; ++kk)
            acc = MFMA32(A[kk], ldfrag(qkv_w + (size_t)(cb + ct * 16 + lm) * CDIM + kk * 32 + lg * 8), acc);
          const float qbias = qkv_b[cb + ct * 16 + lm];
#pragma unroll
          for (int r = 0; r < 4; ++r) qb[j][g][ct][r] = f2bf(acc[r] + qbias);
        }
      }
    }
  }
  __syncthreads();   // xs dead -> U becomes per-wave P slots; kbuf/vbuf ready

  unsigned short* __restrict__ Ps = &U[wv * 1664];         // per-wave [16][104]
  // zero pad cols 98..103 once (P stores below never touch cols >= 98)
  if (lm < 6) {
#pragma unroll
    for (int r = 0; r < 4; ++r) Ps[(lg * 4 + r) * 104 + 98 + lm] = 0;
  }
  // ---- q bounce: C/D layout -> A-frag layout through own P slot ----
  bf16x8 aq[2][2];
#pragma unroll
  for (int r = 0; r < 4; ++r) {
#pragma unroll
    for (int ct = 0; ct < 2; ++ct) {
      Ps[(lg * 4 + r) * 104 +      ct * 16 + lm] = qb[0][0][ct][r];
      Ps[(lg * 4 + r) * 104 + 32 + ct * 16 + lm] = qb[0][1][ct][r];
      if (have1) Ps[(lg * 4 + r) * 104 + 64 + ct * 16 + lm] = qb[1][0][ct][r];
    }
  }
  LGKM0();
  aq[0][0] = *(const bf16x8*)&Ps[lm * 104 +      lg * 8];
  aq[0][1] = *(const bf16x8*)&Ps[lm * 104 + 32 + lg * 8];
  if (have1) {
    aq[1][0] = *(const bf16x8*)&Ps[lm * 104 + 64 + lg * 8];
    LGKM0();
#pragma unroll
    for (int r = 0; r < 4; ++r)
#pragma unroll
      for (int ct = 0; ct < 2; ++ct)
        Ps[(lg * 4 + r) * 104 + ct * 16 + lm] = qb[1][1][ct][r];
    LGKM0();
    aq[1][1] = *(const bf16x8*)&Ps[lm * 104 + lg * 8];
  }

  // ---------------- attention ----------------
#pragma unroll
  for (int g = 0; g < 2; ++g) {
    f32x4 s1[7];
    // ---- phase A: QK^T + softmax for both units (all kbuf reads for group g) ----
#pragma unroll
    for (int j = 0; j < 2; ++j) {
      if (j == 0 || have1) {
        const int mi = j ? mi1 : mi0;
        const int h = 2 * g + (j ? 1 : hh0), cb = h * 32;
        f32x4 s[7];
#pragma unroll
        for (int nj = 0; nj < 7; ++nj) {
          int krow = nj * 16 + lm; if (krow > 97) krow = 97;
          bf16x8 Bf = *(const bf16x8*)&kbuf[swzK(krow, cb + lg * 8)];
          f32x4 z = {0.f,0.f,0.f,0.f};
          s[nj] = MFMA32(aq[j][g], Bf, z);
        }
        bool nval[7]; int mcn[7];
#pragma unroll
        for (int nj = 0; nj < 7; ++nj) {
          int n = nj * 16 + lm;
          nval[nj] = (n < NTOK);
          mcn[nj] = mcode[n];
        }
#pragma unroll
        for (int r = 0; r < 4; ++r) {
          int m = mi * 16 + lg * 4 + r;
          int mc = m < NTOK ? m : NTOK - 1;
          const int mcm = mcode[mc];
          const float* __restrict__ mrow = maskw + mc * NTOK;
          float mx = -1e30f;
#pragma unroll
          for (int nj = 0; nj < 7; ++nj) {
            float val;
            if (nval[nj]) {
              val = s[nj][r] * SCALE + mrow[nj * 16 + lm]
                  + bf2f(rpbL[(mcm - mcn[nj] + 253) * 4 + h]);
            } else val = -1e30f;
            s[nj][r] = val;
            mx = fmaxf(mx, val);
          }
          mx = fmaxf(mx, __shfl_xor(mx, 1));
          mx = fmaxf(mx, __shfl_xor(mx, 2));
          mx = fmaxf(mx, __shfl_xor(mx, 4));
          mx = fmaxf(mx, __shfl_xor(mx, 8));
          float sum = 0.f;
#pragma unroll
          for (int nj = 0; nj < 7; ++nj) {
            float e = __expf(s[nj][r] - mx);
            s[nj][r] = e; sum += e;
          }
          sum += __shfl_xor(sum, 1);
          sum += __shfl_xor(sum, 2);
          sum += __shfl_xor(sum, 4);
          sum += __shfl_xor(sum, 8);
          const float inv = 1.f / sum;
#pragma unroll
          for (int nj = 0; nj < 7; ++nj) s[nj][r] *= inv;
        }
        if (j == 0) {
#pragma unroll
          for (int r = 0; r < 4; ++r) {
#pragma unroll
            for (int nj = 0; nj < 6; ++nj)
              Ps[(lg * 4 + r) * 104 + nj * 16 + lm] = f2bf(s[nj][r]);
            if (lm < 2)                              // cols 96..97 only (98..111 are pads)
              Ps[(lg * 4 + r) * 104 + 96 + lm] = f2bf(s[6][r]);
          }
        } else {
#pragma unroll
          for (int nj = 0; nj < 7; ++nj) s1[nj] = s[nj];
        }
      }
    }
    __syncthreads();   // all kbuf(g) reads done -> o cols [g*64, g*64+64) writable

    // ---- phase B: PV (o -> kbuf overlay) ----
    {
      const int h = 2 * g + hh0;
      LGKM0();         // P(u0) writes visible to own reads
      bf16x4 ap[7];
#pragma unroll
      for (int nj = 0; nj < 6; ++nj)
        ap[nj] = *(const bf16x4*)&Ps[lm * 104 + nj * 16 + lg * 4];
      if (lg < 2) ap[6] = *(const bf16x4*)&Ps[lm * 104 + 96 + lg * 4];
      else { bf16x4 z = {0,0,0,0}; ap[6] = z; }
#pragma unroll
      for (int dt = 0; dt < 2; ++dt) {
        const int d = h * 32 + dt * 16 + lm;
        f32x4 acc = {0.f,0.f,0.f,0.f};
#pragma unroll
        for (int nj = 0; nj < 7; ++nj) {
          int vc = nj < 6 ? nj * 16 + lg * 4 : (lg < 2 ? 96 + lg * 4 : 96);
          bf16x4 bv = *(const bf16x4*)&vbuf[idxV(d, vc)];
          acc = MFMA16(ap[nj], bv, acc);
        }
#pragma unroll
        for (int r = 0; r < 4; ++r) {
          int m = mi0 * 16 + lg * 4 + r;
          if (m < NTOK) kbuf[swzK(m, d)] = f2bf(acc[r]);
        }
      }
    }
    if (have1) {
      LGKM0();         // PV(u0) P reads drained before overwrite
#pragma unroll
      for (int r = 0; r < 4; ++r) {
#pragma unroll
        for (int nj = 0; nj < 6; ++nj)
          Ps[(lg * 4 + r) * 104 + nj * 16 + lm] = f2bf(s1[nj][r]);
        if (lm < 2)
          Ps[(lg * 4 + r) * 104 + 96 + lm] = f2bf(s1[6][r]);
      }
      LGKM0();
      const int h = 2 * g + 1;
      bf16x4 ap[7];
#pragma unroll
      for (int nj = 0; nj < 6; ++nj)
        ap[nj] = *(const bf16x4*)&Ps[lm * 104 + nj * 16 + lg * 4];
      if (lg < 2) ap[6] = *(const bf16x4*)&Ps[lm * 104 + 96 + lg * 4];
      else { bf16x4 z = {0,0,0,0}; ap[6] = z; }
#pragma unroll
      for (int dt = 0; dt < 2; ++dt) {
        const int d = h * 32 + dt * 16 + lm;
        f32x4 acc = {0.f,0.f,0.f,0.f};
#pragma unroll
        for (int nj = 0; nj < 7; ++nj) {
          int vc = nj < 6 ? nj * 16 + lg * 4 : (lg < 2 ? 96 + lg * 4 : 96);
          bf16x4 bv = *(const bf16x4*)&vbuf[idxV(d, vc)];
          acc = MFMA16(ap[nj], bv, acc);
        }
#pragma unroll
        for (int r = 0; r < 4; ++r) {
          int m = mi1 * 16 + lg * 4 + r;
          if (m < NTOK) kbuf[swzK(m, d)] = f2bf(acc[r]);
        }
      }
    }
    __syncthreads();   // o(g) complete (also gates g=1 reads / GEMM3)
  }

  // ---------------- GEMM3: out = o @ Wproj^T + b (o lives in kbuf) ----------------
  {
    bf16x8 Bp[4];
#pragma unroll
    for (int kk = 0; kk < 4; ++kk)
      Bp[kk] = ldfrag(proj_w + (size_t)(wv * 16 + lm) * CDIM + kk * 32 + lg * 8);
    const float pb = proj_b[wv * 16 + lm];
    float* __restrict__ outb = out + (size_t)blk * (NTOK * CDIM);
    for (int mi = 0; mi < 7; ++mi) {
      int arow = mi * 16 + lm; if (arow > 97) arow = 97;
      f32x4 acc = {0.f,0.f,0.f,0.f};
#pragma unroll
      for (int kk = 0; kk < 4; ++kk) {
        bf16x8 A = *(const bf16x8*)&kbuf[swzK(arow, kk * 32 + lg * 8)];
        acc = MFMA32(A, Bp[kk], acc);
      }
#pragma unroll
      for (int r = 0; r < 4; ++r) {
        int m = mi * 16 + lg * 4 + r;
        if (m < NTOK) outb[m * CDIM + wv * 16 + lm] = acc[r] + pb;
      }
    }
  }
}

extern "C" void kernel_launch(void* const* d_in, const int* in_sizes, int n_in,
                              void* d_out, int out_size, void* d_ws, size_t ws_size,
                              hipStream_t stream) {
  const float* x      = (const float*)d_in[0];
  const float* mask   = (const float*)d_in[1];
  const float* qkv_w  = (const float*)d_in[2];
  const float* qkv_b  = (const float*)d_in[3];
  const float* rpb    = (const float*)d_in[4];
  const float* proj_w = (const float*)d_in[5];
  const float* proj_b = (const float*)d_in[6];
  int B  = in_sizes[0] / (NTOK * CDIM);
  int nW = in_sizes[1] / (NTOK * NTOK);
  hipLaunchKernelGGL(win_attn_kernel, dim3(B), dim3(512), 0, stream,
                     x, mask, qkv_w, qkv_b, rpb, proj_w, proj_b, (float*)d_out, nW);
}

// Round 7
// 135.052 us; speedup vs baseline: 4.5182x; 2.0892x over previous
//
#include <hip/hip_runtime.h>
#include <hip/hip_bf16.h>

#define NTOK 98
#define CDIM 128
#define SCALE 0.17677669529663687f
#define NEG_BIG -1e30f
#define CMBW 112   // cmb row width: must cover full fragment n-range 0..111 (R6 bug: 104)

typedef short bf16x8 __attribute__((ext_vector_type(8)));
typedef short bf16x4 __attribute__((ext_vector_type(4)));
typedef float f32x4 __attribute__((ext_vector_type(4)));

#define MFMA32(a,b,c) __builtin_amdgcn_mfma_f32_16x16x32_bf16(a,b,c,0,0,0)

#if __has_builtin(__builtin_amdgcn_mfma_f32_16x16x16_bf16)
#define MFMA16(a,b,c) __builtin_amdgcn_mfma_f32_16x16x16_bf16(a,b,c,0,0,0)
#elif __has_builtin(__builtin_amdgcn_mfma_f32_16x16x16bf16_1k)
#define MFMA16(a,b,c) __builtin_amdgcn_mfma_f32_16x16x16bf16_1k(a,b,c,0,0,0)
#else
__device__ __forceinline__ f32x4 mfma16_asm(bf16x4 a, bf16x4 b, f32x4 c) {
  asm("v_mfma_f32_16x16x16_bf16 %0, %1, %2, %0" : "+v"(c) : "v"(a), "v"(b));
  return c;
}
#define MFMA16(a,b,c) mfma16_asm(a,b,c)
#endif

__device__ __forceinline__ unsigned short f2bf(float f) {
  __hip_bfloat16 h = __float2bfloat16(f);          // native HW cvt
  return __builtin_bit_cast(unsigned short, h);
}
__device__ __forceinline__ float bf2f(unsigned short b) {
  union { unsigned u; float f; } v; v.u = ((unsigned)b) << 16; return v.f;
}

// stride-128 LDS tiles: XOR elem bits 3..5 by row -> b64/b128-safe, kills the
// 256B-stride bank conflict (G4/T2).
__device__ __forceinline__ int swzK(int row, int col) {
  return row * 128 + (col ^ ((row & 7) << 3));
}

__device__ __forceinline__ bf16x8 ldfrag(const float* __restrict__ p) {
  float4 a = *(const float4*)p;
  float4 b = *(const float4*)(p + 4);
  bf16x8 fr;
  fr[0]=(short)f2bf(a.x); fr[1]=(short)f2bf(a.y); fr[2]=(short)f2bf(a.z); fr[3]=(short)f2bf(a.w);
  fr[4]=(short)f2bf(b.x); fr[5]=(short)f2bf(b.y); fr[6]=(short)f2bf(b.z); fr[7]=(short)f2bf(b.w);
  return fr;
}

__device__ __forceinline__ int pcode(int t) {       // rel-pos code
  int d = t / 49, r = t % 49;
  return d * 169 + (r / 7) * 13 + (r % 7);
}

// ---------------- prep 1: weights -> bf16 fragment-order, biases (scale folded) ----------------
__global__ __launch_bounds__(512)
void prep_w(const float* __restrict__ qkv_w, const float* __restrict__ qkv_b,
            const float* __restrict__ proj_w, const float* __restrict__ proj_b,
            unsigned short* __restrict__ qpre, unsigned short* __restrict__ ppre,
            float* __restrict__ bpre)
{
  int gid = blockIdx.x * 512 + threadIdx.x;
  if (gid < 6144) {                                  // qkv: 24 row-tiles x 4 kk x 64 lanes
    int t = gid >> 8, rem = gid & 255, kk = rem >> 6, ln = rem & 63;
    int row = t * 16 + (ln & 15), col = kk * 32 + (ln >> 4) * 8;
    float sc = (row < CDIM) ? SCALE : 1.f;           // fold softmax scale into Wq
    const float* s = qkv_w + (size_t)row * CDIM + col;
    unsigned short* d = qpre + (size_t)gid * 8;
#pragma unroll
    for (int e = 0; e < 8; ++e) d[e] = f2bf(s[e] * sc);
  } else if (gid < 8192) {                           // proj: 8 row-tiles
    int f2 = gid - 6144;
    int t = f2 >> 8, rem = f2 & 255, kk = rem >> 6, ln = rem & 63;
    const float* s = proj_w + (size_t)(t * 16 + (ln & 15)) * CDIM + kk * 32 + (ln >> 4) * 8;
    unsigned short* d = ppre + (size_t)f2 * 8;
#pragma unroll
    for (int e = 0; e < 8; ++e) d[e] = f2bf(s[e]);
  } else {                                           // biases (512 values)
    int i = gid - 8192;
    if (i < 384) bpre[i] = qkv_b[i] * (i < CDIM ? SCALE : 1.f);
    else if (i < 512) bpre[i] = proj_b[i - 384];
  }
}

// ---------------- prep 2: cmb[w][h][m][0..111] = mask + rpb_bias (pads = -1e30) ----------------
__global__ __launch_bounds__(256)
void prep_cmb(const float* __restrict__ mask, const float* __restrict__ rpb,
              float* __restrict__ cmb, int nW)
{
  const int total = 256 * NTOK * CMBW;               // (w,h) x m x n-padded
  for (int idx = blockIdx.x * 256 + threadIdx.x; idx < total; idx += gridDim.x * 256) {
    int row = idx / CMBW, n = idx - row * CMBW;
    int wh = row / NTOK, m = row - wh * NTOK;
    int w = wh >> 2, h = wh & 3;
    float v = NEG_BIG;
    if (n < NTOK)
      v = mask[((size_t)w * NTOK + m) * NTOK + n] + rpb[(pcode(m) - pcode(n) + 253) * 4 + h];
    cmb[idx] = v;
  }
}

// ---------------- main kernel ----------------
template<bool PRE>
__global__ __launch_bounds__(512, 4)
void win_attn(const float* __restrict__ x, const float* __restrict__ mask,
              const float* __restrict__ qkv_w, const float* __restrict__ qkv_b,
              const float* __restrict__ rpb, const float* __restrict__ proj_w,
              const float* __restrict__ proj_b, float* __restrict__ out, int nW,
              const float* __restrict__ cmb, const unsigned short* __restrict__ qpre,
              const unsigned short* __restrict__ ppre, const float* __restrict__ bpre)
{
  __shared__ __align__(16) unsigned short xs[(PRE ? 112 : 98) * 128]; // x; later o
  __shared__ __align__(16) unsigned short kbuf[98 * 128];             // k [tok][chan]
  __shared__ __align__(16) unsigned short vbuf[128 * 100];            // v^T [chan][tok]
  __shared__ unsigned short rpbL[PRE ? 2 : 2028];
  __shared__ short mcode[PRE ? 2 : 112];

  const int tid = threadIdx.x;
  const int lane = tid & 63;
  const int wv = tid >> 6;
  const int lm = lane & 15;
  const int lg = lane >> 4;
  const int blk = blockIdx.x;
  const int wmod = blk % nW;
  const float* __restrict__ xblk = x + (size_t)blk * (NTOK * CDIM);
  const float* __restrict__ maskw = mask + (size_t)wmod * (NTOK * NTOK);

  if constexpr (!PRE) {
    if (tid < 112) mcode[tid] = (short)(tid < NTOK ? pcode(tid) : 0);
    for (int i = tid; i < 2028; i += 512) rpbL[i] = f2bf(rpb[i]);
  }
  for (int v = tid; v < NTOK * 32; v += 512) {       // stage x -> xs (bf16, swizzled)
    int row = v >> 5, c4 = (v & 31) << 2;
    float4 f = *(const float4*)(xblk + row * CDIM + c4);
    uint2 u;
    u.x = (unsigned)f2bf(f.x) | ((unsigned)f2bf(f.y) << 16);
    u.y = (unsigned)f2bf(f.z) | ((unsigned)f2bf(f.w) << 16);
    *(uint2*)&xs[swzK(row, c4)] = u;
  }
  __syncthreads();

  // weight fragment accessors
  auto wq = [&](int t, int kk) -> bf16x8 {           // qkv rows (t<8: q pre-scaled)
    if constexpr (PRE) return *(const bf16x8*)&qpre[(size_t)((t * 4 + kk) * 64 + lane) * 8];
    else return ldfrag(qkv_w + (size_t)(t * 16 + lm) * CDIM + kk * 32 + lg * 8);
  };

  // ---------------- prologue: k (swapped, b64 stores), v (normal, b64 stores), q -> regs ----------------
  {
    bf16x8 Bk[4], Bv[4];
#pragma unroll
    for (int kk = 0; kk < 4; ++kk) { Bk[kk] = wq(8 + wv, kk); Bv[kk] = wq(16 + wv, kk); }
    const float4 bk4 = *(const float4*)((PRE ? bpre : qkv_b) + CDIM + wv * 16 + lg * 4);
    const float  bv_ = (PRE ? bpre : qkv_b)[2 * CDIM + wv * 16 + lm];
    for (int mi = 0; mi < 7; ++mi) {
      int arow = mi * 16 + lm; if (arow > 97) arow = 97;
      bf16x8 A[4];
#pragma unroll
      for (int kk = 0; kk < 4; ++kk) A[kk] = *(const bf16x8*)&xs[swzK(arow, kk * 32 + lg * 8)];
      f32x4 ak = {0.f,0.f,0.f,0.f}, av = {0.f,0.f,0.f,0.f};
#pragma unroll
      for (int kk = 0; kk < 4; ++kk) {
        ak = MFMA32(Bk[kk], A[kk], ak);              // swapped: row=chan, col=token
        av = MFMA32(A[kk], Bv[kk], av);              // normal:  row=token, col=chan
      }
      int ktok = mi * 16 + lm;
      if (ktok < NTOK) {
        bf16x4 pk;
#pragma unroll
        for (int r = 0; r < 4; ++r) pk[r] = (short)f2bf(ak[r] + ((const float*)&bk4)[r]);
        *(bf16x4*)&kbuf[swzK(ktok, wv * 16 + lg * 4)] = pk;
      }
      int vtok0 = mi * 16 + lg * 4;
      if (vtok0 < 100) {                             // cols 98..99 get finite pad data
        bf16x4 pv;
#pragma unroll
        for (int r = 0; r < 4; ++r) pv[r] = (short)f2bf(av[r] + bv_);
        *(bf16x4*)&vbuf[(size_t)(wv * 16 + lm) * 100 + vtok0] = pv;
      }
    }
  }

  const bool have1 = (wv < 6);
  const int hh0 = wv / 7, mi0 = wv % 7;
  const int mi1 = wv + 1;                            // unit u1: hh=1 (when wv<6)

  // q (swapped): lane holds q[tok=lm][chan] as B-frags for MFMA16 QK^T
  bf16x4 bq[2][2][2];                                // [j][g][ct]
#pragma unroll
  for (int j = 0; j < 2; ++j) {
    if (j == 0 || have1) {
      const int mi = j ? mi1 : mi0, hh = j ? 1 : hh0;
      int arow = mi * 16 + lm; if (arow > 97) arow = 97;
      bf16x8 Xf[4];
#pragma unroll
      for (int kk = 0; kk < 4; ++kk) Xf[kk] = *(const bf16x8*)&xs[swzK(arow, kk * 32 + lg * 8)];
#pragma unroll
      for (int g = 0; g < 2; ++g) {
        const int h = 2 * g + hh;
#pragma unroll
        for (int ct = 0; ct < 2; ++ct) {
          const int t = h * 2 + ct;                  // q row-tile (rows h*32+ct*16 ..)
          f32x4 acc = {0.f,0.f,0.f,0.f};
#pragma unroll
          for (int kk = 0; kk < 4; ++kk) acc = MFMA32(wq(t, kk), Xf[kk], acc);
          const float4 qb4 = *(const float4*)((PRE ? bpre : qkv_b) + t * 16 + lg * 4);
#pragma unroll
          for (int r = 0; r < 4; ++r) {
            float vq = acc[r] + ((const float*)&qb4)[r];
            if constexpr (!PRE) vq *= SCALE;
            bq[j][g][ct][r] = (short)f2bf(vq);
          }
        }
      }
    }
  }
  __syncthreads();   // xs reads done (o overlay ok); kbuf/vbuf ready (read-only now)

  // ---------------- attention: barrier-free (o -> xs overlay) ----------------
#pragma unroll
  for (int g = 0; g < 2; ++g) {
#pragma unroll
    for (int j = 0; j < 2; ++j) {
      if (j == 0 || have1) {
        const int mi = j ? mi1 : mi0, hh = j ? 1 : hh0;
        const int h = 2 * g + hh, cb = h * 32;
        f32x4 s[7];
#pragma unroll
        for (int nj = 0; nj < 7; ++nj) {             // QK^T swapped: col=m(lm), row=n
          int krow = nj * 16 + lm; if (krow > 97) krow = 97;
          bf16x4 k0 = *(const bf16x4*)&kbuf[swzK(krow, cb + lg * 4)];
          bf16x4 k1 = *(const bf16x4*)&kbuf[swzK(krow, cb + 16 + lg * 4)];
          f32x4 z = {0.f,0.f,0.f,0.f};
          z = MFMA16(k0, bq[j][g][0], z);
          s[nj] = MFMA16(k1, bq[j][g][1], z);
        }
        const int m = mi * 16 + lm;
        const int mclamp = m > 97 ? 97 : m;
        float sum = 0.f;
        if constexpr (PRE) {                         // bias+mask: one float4 per nj
          const float* __restrict__ cp =
              cmb + ((size_t)(wmod * 4 + h) * NTOK + mclamp) * CMBW + lg * 4;
#pragma unroll
          for (int nj = 0; nj < 7; ++nj) {
            float4 cv = *(const float4*)(cp + nj * 16);
#pragma unroll
            for (int r = 0; r < 4; ++r) {
              float e = __expf(s[nj][r] + ((const float*)&cv)[r]);  // no-max softmax
              s[nj][r] = e; sum += e;
            }
          }
        } else {
          const int cm4 = ((int)mcode[mclamp]) * 4 + h + 1012;
          const float* __restrict__ mrow = maskw + mclamp * NTOK;
#pragma unroll
          for (int nj = 0; nj < 7; ++nj) {
            const int n0 = nj * 16 + lg * 4;
#pragma unroll
            for (int r = 0; r < 4; ++r) {
              int n = n0 + r;
              float val = NEG_BIG;
              if (n < NTOK) val = s[nj][r] + mrow[n] + bf2f(rpbL[cm4 - ((int)mcode[n]) * 4]);
              float e = __expf(val);
              s[nj][r] = e; sum += e;
            }
          }
        }
        sum += __shfl_xor(sum, 16);
        sum += __shfl_xor(sum, 32);
        const float inv = 1.f / sum;
        bf16x4 pp[7];                                // P A-frags, in-register
#pragma unroll
        for (int nj = 0; nj < 7; ++nj) {
#pragma unroll
          for (int r = 0; r < 4; ++r) pp[nj][r] = (short)f2bf(s[nj][r] * inv);
        }
        // PV: out[m][d], d = cb + dt*16 + lm; writes into xs overlay
#pragma unroll
        for (int dt = 0; dt < 2; ++dt) {
          const int d = cb + dt * 16 + lm;
          f32x4 acc = {0.f,0.f,0.f,0.f};
#pragma unroll
          for (int nj = 0; nj < 7; ++nj) {
            const int vc = nj < 6 ? nj * 16 + lg * 4 : 96;   // clamp: P=0 there
            bf16x4 bv = *(const bf16x4*)&vbuf[(size_t)d * 100 + vc];
            acc = MFMA16(pp[nj], bv, acc);
          }
#pragma unroll
          for (int r = 0; r < 4; ++r) {
            int m2 = mi * 16 + lg * 4 + r;
            if (PRE || m2 < NTOK) xs[swzK(m2, d)] = f2bf(acc[r]);
          }
        }
      }
    }
  }
  __syncthreads();   // o complete

  // ---------------- GEMM3 (swapped): out = o @ Wp^T, float4 stores ----------------
  {
    bf16x8 Bp[4];
#pragma unroll
    for (int kk = 0; kk < 4; ++kk) {
      if constexpr (PRE) Bp[kk] = *(const bf16x8*)&ppre[(size_t)((wv * 4 + kk) * 64 + lane) * 8];
      else Bp[kk] = ldfrag(proj_w + (size_t)(wv * 16 + lm) * CDIM + kk * 32 + lg * 8);
    }
    const float4 pb4 = *(const float4*)((PRE ? bpre + 384 : proj_b) + wv * 16 + lg * 4);
    float* __restrict__ outb = out + (size_t)blk * (NTOK * CDIM);
    for (int mi = 0; mi < 7; ++mi) {
      int orow = mi * 16 + lm;
      if (!PRE && orow > 97) orow = 97;
      f32x4 acc = {0.f,0.f,0.f,0.f};
#pragma unroll
      for (int kk = 0; kk < 4; ++kk) {
        bf16x8 Bo = *(const bf16x8*)&xs[swzK(orow, kk * 32 + lg * 8)];
        acc = MFMA32(Bp[kk], Bo, acc);               // row=out-chan, col=token
      }
      int tok = mi * 16 + lm;
      if (tok < NTOK) {
        float4 o4;
        o4.x = acc[0] + pb4.x; o4.y = acc[1] + pb4.y;
        o4.z = acc[2] + pb4.z; o4.w = acc[3] + pb4.w;
        *(float4*)(outb + (size_t)tok * CDIM + wv * 16 + lg * 4) = o4;
      }
    }
  }
}

extern "C" void kernel_launch(void* const* d_in, const int* in_sizes, int n_in,
                              void* d_out, int out_size, void* d_ws, size_t ws_size,
                              hipStream_t stream) {
  const float* x      = (const float*)d_in[0];
  const float* mask   = (const float*)d_in[1];
  const float* qkv_w  = (const float*)d_in[2];
  const float* qkv_b  = (const float*)d_in[3];
  const float* rpb    = (const float*)d_in[4];
  const float* proj_w = (const float*)d_in[5];
  const float* proj_b = (const float*)d_in[6];
  int B  = in_sizes[0] / (NTOK * CDIM);
  int nW = in_sizes[1] / (NTOK * NTOK);

  const size_t CMB_B  = (size_t)256 * NTOK * CMBW * 4;  // 11,239,424
  const size_t QPRE_B = 24 * 4 * 64 * 8 * 2;            // 98,304
  const size_t PPRE_B = 8 * 4 * 64 * 8 * 2;             // 32,768
  const size_t BIAS_B = 512 * 4;
  const size_t need = CMB_B + QPRE_B + PPRE_B + BIAS_B;

  if (ws_size >= need) {
    float* cmb = (float*)d_ws;
    unsigned short* qpre = (unsigned short*)((char*)d_ws + CMB_B);
    unsigned short* ppre = (unsigned short*)((char*)d_ws + CMB_B + QPRE_B);
    float* bpre = (float*)((char*)d_ws + CMB_B + QPRE_B + PPRE_B);
    hipLaunchKernelGGL(prep_w, dim3(17), dim3(512), 0, stream,
                       qkv_w, qkv_b, proj_w, proj_b, qpre, ppre, bpre);
    hipLaunchKernelGGL(prep_cmb, dim3(1024), dim3(256), 0, stream, mask, rpb, cmb, nW);
    hipLaunchKernelGGL(win_attn<true>, dim3(B), dim3(512), 0, stream,
                       x, mask, qkv_w, qkv_b, rpb, proj_w, proj_b, (float*)d_out, nW,
                       cmb, qpre, ppre, bpre);
  } else {
    hipLaunchKernelGGL(win_attn<false>, dim3(B), dim3(512), 0, stream,
                       x, mask, qkv_w, qkv_b, rpb, proj_w, proj_b, (float*)d_out, nW,
                       (const float*)nullptr, (const unsigned short*)nullptr,
                       (const unsigned short*)nullptr, (const float*)nullptr);
  }
}